// Round 1
// baseline (476.244 us; speedup 1.0000x reference)
//
#include <hip/hip_runtime.h>

#define Bn 8
#define Cn 3
#define Sn 1024
#define DIMn 768
#define Hn 3
#define HDn 256
#define BCHn 72

typedef __bf16 bf16x8 __attribute__((ext_vector_type(8)));
typedef float f32x4 __attribute__((ext_vector_type(4)));
typedef unsigned short u16x8 __attribute__((ext_vector_type(8)));
typedef unsigned short u16x4 __attribute__((ext_vector_type(4)));

static __device__ __forceinline__ unsigned short f2bf(float f){
  unsigned u = __builtin_bit_cast(unsigned, f);
  u += 0x7fffu + ((u >> 16) & 1u);
  return (unsigned short)(u >> 16);
}
static __device__ __forceinline__ u16x4 cvt4(float4 v){
  u16x4 r = { f2bf(v.x), f2bf(v.y), f2bf(v.z), f2bf(v.w) };
  return r;
}
static __device__ __forceinline__ bf16x8 ld8(const unsigned short* p){
  return __builtin_bit_cast(bf16x8, *(const u16x8*)p);
}

// ---------------- Kernel 1: K and V^T projections ----------------
// job 0: K[t][e]  = sum_d X[t,d] Wk[e,d] + bk[e]   (A=X rows, B=Wk rows)
// job 1: Vt[e][t] = sum_d Wv[e,d] X[t,d] + bv[e]   (A=Wv rows, B=X rows)
__global__ __launch_bounds__(256) void projkv(
    const float* __restrict__ x,
    const float* __restrict__ Wk, const float* __restrict__ bk,
    const float* __restrict__ Wv, const float* __restrict__ bv,
    unsigned short* __restrict__ Kw, unsigned short* __restrict__ Vt)
{
  __shared__ unsigned short Al[128*40]; // [128][32+8]
  __shared__ unsigned short Bl[128*40];
  const int tid = threadIdx.x, lane = tid & 63, wave = tid >> 6;
  const int bch = blockIdx.z;
  const int h = bch % Hn, c = (bch / Hn) % Cn, b = bch / (Hn*Cn);
  const long xbase = ((long)(b*Cn + c) * Sn) * DIMn + h * HDn;
  const int job = blockIdx.y;
  const float *aP, *bP, *biasP;
  int aStr, bStr, mbase, nbase, ldc;
  if (job == 0){
    aP = x + xbase;        aStr = DIMn; mbase = (blockIdx.x >> 1) * 128;
    bP = Wk + h*HDn*HDn;   bStr = HDn;  nbase = (blockIdx.x & 1) * 128;
    biasP = bk + h*HDn;    ldc = HDn;
  } else {
    aP = Wv + h*HDn*HDn;   aStr = HDn;  mbase = (blockIdx.x & 1) * 128;
    bP = x + xbase;        bStr = DIMn; nbase = (blockIdx.x >> 1) * 128;
    biasP = bv + h*HDn;    ldc = Sn;
  }
  unsigned short* outP = (job == 0 ? Kw : Vt) + (long)bch * Sn * HDn;

  f32x4 acc[4][4] = {};
  const int wm = (wave >> 1) * 64, wn = (wave & 1) * 64;
  const int kr = (lane >> 4) * 8;
  const int l15 = lane & 15;

  for (int ks = 0; ks < 8; ++ks){
    const int k0 = ks * 32;
    #pragma unroll
    for (int i = 0; i < 4; ++i){
      int id = tid + i*256, row = id >> 3, f4 = (id & 7) * 4;
      float4 va = *(const float4*)(aP + (long)(mbase + row) * aStr + k0 + f4);
      *(u16x4*)&Al[row*40 + f4] = cvt4(va);
      float4 vb = *(const float4*)(bP + (long)(nbase + row) * bStr + k0 + f4);
      *(u16x4*)&Bl[row*40 + f4] = cvt4(vb);
    }
    __syncthreads();
    bf16x8 af[4], bfr[4];
    #pragma unroll
    for (int t = 0; t < 4; ++t){
      af[t]  = ld8(&Al[(wm + t*16 + l15)*40 + kr]);
      bfr[t] = ld8(&Bl[(wn + t*16 + l15)*40 + kr]);
    }
    #pragma unroll
    for (int sm = 0; sm < 4; ++sm)
      #pragma unroll
      for (int sn = 0; sn < 4; ++sn)
        acc[sm][sn] = __builtin_amdgcn_mfma_f32_16x16x32_bf16(af[sm], bfr[sn], acc[sm][sn], 0, 0, 0);
    __syncthreads();
  }
  #pragma unroll
  for (int sm = 0; sm < 4; ++sm){
    #pragma unroll
    for (int sn = 0; sn < 4; ++sn){
      const int col = nbase + wn + sn*16 + l15;
      #pragma unroll
      for (int r = 0; r < 4; ++r){
        const int row = mbase + wm + sm*16 + (lane >> 4)*4 + r;
        float v = acc[sm][sn][r] + (job ? biasP[row] : biasP[col]);
        outP[(long)row * ldc + col] = f2bf(v);
      }
    }
  }
}

// ---------------- Kernel 2: fused Q projection + flash attention ----------------
// Block = one (bch, 64-row Q tile). 4 waves, each owns 16 Q rows.
__global__ __launch_bounds__(256) void attn(
    const float* __restrict__ x,
    const float* __restrict__ Wq, const float* __restrict__ bq,
    const unsigned short* __restrict__ Kw, const unsigned short* __restrict__ Vt,
    float* __restrict__ out)
{
  __shared__ alignas(16) unsigned char smem[54272];
  unsigned short* XQ = (unsigned short*)smem;            // phase A: X [64][264]; then Q [64][264]
  unsigned short* WL = (unsigned short*)(smem + 33792);  // [256][40]
  unsigned short* KL = (unsigned short*)smem;            // phase B: [32][264]
  unsigned short* VL = (unsigned short*)(smem + 16896);  // [256][40]
  unsigned short* PL = (unsigned short*)(smem + 37376);  // [4][16][40]

  const int tid = threadIdx.x, lane = tid & 63, wave = tid >> 6;
  const int bid = blockIdx.x;
  // XCD-locality swizzle: all 16 q-tiles of a bch share bid%8 and are adjacent in dispatch
  const int idx0 = bid >> 3;
  const int bch = (idx0 >> 4) * 8 + (bid & 7);
  const int qt  = idx0 & 15;
  const int h = bch % Hn, c = (bch / Hn) % Cn, b = bch / (Hn*Cn);
  const long xbase = ((long)(b*Cn + c) * Sn) * DIMn + h * HDn;
  const int q0 = qt * 64;
  const int kr = (lane >> 4) * 8;
  const int l15 = lane & 15;

  // ---- Phase A: Q = (X_tile @ Wq^T + bq) * scale, kept as A-fragments ----
  #pragma unroll
  for (int i = 0; i < 16; ++i){
    int id = tid + i*256, row = id >> 6, f4 = (id & 63) * 4;
    float4 v = *(const float4*)(x + xbase + (long)(q0 + row) * DIMn + f4);
    *(u16x4*)&XQ[row*264 + f4] = cvt4(v);
  }
  __syncthreads();

  f32x4 qa[16] = {};
  const float* Wqh = Wq + h*HDn*HDn;
  for (int ks = 0; ks < 8; ++ks){
    const int k0 = ks * 32;
    #pragma unroll
    for (int i = 0; i < 8; ++i){
      int id = tid + i*256, e = id >> 3, f4 = (id & 7) * 4;
      float4 v = *(const float4*)(Wqh + e*HDn + k0 + f4);
      *(u16x4*)&WL[e*40 + f4] = cvt4(v);
    }
    __syncthreads();
    bf16x8 a = ld8(&XQ[(wave*16 + l15)*264 + k0 + kr]);
    #pragma unroll
    for (int nt = 0; nt < 16; ++nt){
      bf16x8 bb = ld8(&WL[(nt*16 + l15)*40 + kr]);
      qa[nt] = __builtin_amdgcn_mfma_f32_16x16x32_bf16(a, bb, qa[nt], 0, 0, 0);
    }
    __syncthreads();
  }
  const float scale = 0.0625f; // 1/sqrt(256)
  #pragma unroll
  for (int nt = 0; nt < 16; ++nt){
    float bias = bq[h*HDn + nt*16 + l15];
    #pragma unroll
    for (int r = 0; r < 4; ++r){
      int row = wave*16 + (lane >> 4)*4 + r;  // C-layout -> LDS
      XQ[row*264 + nt*16 + l15] = f2bf((qa[nt][r] + bias) * scale);
    }
  }
  __syncthreads();
  bf16x8 qf[8];
  #pragma unroll
  for (int k = 0; k < 8; ++k)
    qf[k] = ld8(&XQ[(wave*16 + l15)*264 + k*32 + kr]); // A-layout fragments
  __syncthreads();

  // ---- Phase B: flash loop over 32-wide KV chunks ----
  f32x4 o[16] = {};
  float mI[4], lI[4];
  #pragma unroll
  for (int r = 0; r < 4; ++r){ mI[r] = -1e30f; lI[r] = 0.0f; }
  const unsigned short* Kb = Kw + (long)bch * Sn * HDn;
  const unsigned short* Vb = Vt + (long)bch * Sn * HDn;

  for (int jt = 0; jt < 32; ++jt){
    const int t0 = jt * 32;
    #pragma unroll
    for (int i = 0; i < 4; ++i){
      int id = tid + i*256, row = id >> 5, c8 = (id & 31) * 8;
      *(u16x8*)&KL[row*264 + c8] = *(const u16x8*)(Kb + (long)(t0 + row)*HDn + c8);
    }
    #pragma unroll
    for (int i = 0; i < 4; ++i){
      int id = tid + i*256, e = id >> 2, c8 = (id & 3) * 8;
      *(u16x8*)&VL[e*40 + c8] = *(const u16x8*)(Vb + (long)e*Sn + t0 + c8);
    }
    __syncthreads();

    f32x4 s0 = {}, s1 = {};
    #pragma unroll
    for (int k = 0; k < 8; ++k){
      bf16x8 b0 = ld8(&KL[l15*264 + k*32 + kr]);
      bf16x8 b1 = ld8(&KL[(16 + l15)*264 + k*32 + kr]);
      s0 = __builtin_amdgcn_mfma_f32_16x16x32_bf16(qf[k], b0, s0, 0, 0, 0);
      s1 = __builtin_amdgcn_mfma_f32_16x16x32_bf16(qf[k], b1, s1, 0, 0, 0);
    }

    unsigned short* Pw = PL + wave * (16*40); // per-wave buffer: no barrier needed
    #pragma unroll
    for (int r = 0; r < 4; ++r){
      float v = fmaxf(s0[r], s1[r]);
      v = fmaxf(v, __shfl_xor(v, 1));
      v = fmaxf(v, __shfl_xor(v, 2));
      v = fmaxf(v, __shfl_xor(v, 4));
      v = fmaxf(v, __shfl_xor(v, 8));
      float mn = fmaxf(mI[r], v);
      float al = __expf(mI[r] - mn);
      mI[r] = mn;
      float p0 = __expf(s0[r] - mn);
      float p1 = __expf(s1[r] - mn);
      float rs = p0 + p1;
      rs += __shfl_xor(rs, 1);
      rs += __shfl_xor(rs, 2);
      rs += __shfl_xor(rs, 4);
      rs += __shfl_xor(rs, 8);
      lI[r] = lI[r]*al + rs;
      int row = (lane >> 4)*4 + r;
      Pw[row*40 + l15]      = f2bf(p0);
      Pw[row*40 + 16 + l15] = f2bf(p1);
      #pragma unroll
      for (int nt = 0; nt < 16; ++nt) o[nt][r] *= al;
    }
    bf16x8 pf = ld8(&Pw[l15*40 + kr]); // C-layout -> A-layout via per-wave LDS
    #pragma unroll
    for (int nt = 0; nt < 16; ++nt){
      bf16x8 vf = ld8(&VL[(nt*16 + l15)*40 + kr]);
      o[nt] = __builtin_amdgcn_mfma_f32_16x16x32_bf16(pf, vf, o[nt], 0, 0, 0);
    }
    __syncthreads();
  }

  #pragma unroll
  for (int r = 0; r < 4; ++r){
    int srow = q0 + wave*16 + (lane >> 4)*4 + r;
    float invl = 1.0f / lI[r];
    float* op = out + ((long)(b*Sn + srow)*Cn + c)*DIMn + h*HDn;
    #pragma unroll
    for (int nt = 0; nt < 16; ++nt)
      op[nt*16 + l15] = o[nt][r] * invl;
  }
}

extern "C" void kernel_launch(void* const* d_in, const int* in_sizes, int n_in,
                              void* d_out, int out_size, void* d_ws, size_t ws_size,
                              hipStream_t stream) {
  const float* x  = (const float*)d_in[0];
  const float* Wq = (const float*)d_in[1];
  const float* bq = (const float*)d_in[2];
  const float* Wk = (const float*)d_in[3];
  const float* bk = (const float*)d_in[4];
  const float* Wv = (const float*)d_in[5];
  const float* bv = (const float*)d_in[6];
  float* out = (float*)d_out;
  unsigned short* Kw = (unsigned short*)d_ws;                 // [72][1024][256] bf16
  unsigned short* Vt = Kw + (size_t)BCHn * Sn * HDn;          // [72][256][1024] bf16

  dim3 g1(16, 2, BCHn);
  projkv<<<g1, 256, 0, stream>>>(x, Wk, bk, Wv, bv, Kw, Vt);
  attn<<<dim3(BCHn * 16), 256, 0, stream>>>(x, Wq, bq, Kw, Vt, out);
}